// Round 10
// baseline (281.114 us; speedup 1.0000x reference)
//
#include <hip/hip_runtime.h>
#include <stdint.h>

// Problem constants
#define DIMD 512
#define HEADS 8
#define DHEAD 64
#define NSEQ 256
#define NGRP 256                 // b*p = 4*64
#define TRIPLE 1536
#define ATT_SCALE 0.125f         // 64^-0.5

typedef float f32x4 __attribute__((ext_vector_type(4)));
typedef _Float16 half8 __attribute__((ext_vector_type(8)));
typedef _Float16 half4 __attribute__((ext_vector_type(4)));

// async global->LDS, 16B per lane; LDS dest = per-wave uniform base + lane*16
#define GLD16(gp, lp) __builtin_amdgcn_global_load_lds( \
    (const __attribute__((address_space(1))) void*)(gp), \
    (__attribute__((address_space(3))) void*)(lp), 16, 0, 0)
#define BAR() __builtin_amdgcn_s_barrier()
#define VMW(n) asm volatile("s_waitcnt vmcnt(" #n ")" ::: "memory")
#define LGKM0() asm volatile("s_waitcnt lgkmcnt(0)" ::: "memory")

// ---------------------------------------------------------------------------
// Kernel 0+1 merged: blocks 0..255 = tiled 64x64 LDS transpose of weights;
// blocks 256..16639 = LayerNorm (wave per row).
// ---------------------------------------------------------------------------
__global__ __launch_bounds__(256) void k_pre(const float* __restrict__ x,
                                             const float* __restrict__ g,
                                             const float* __restrict__ b,
                                             const float* __restrict__ wq,
                                             const float* __restrict__ wo,
                                             _Float16* __restrict__ xn,
                                             _Float16* __restrict__ wtq,
                                             _Float16* __restrict__ wto) {
  int bid = blockIdx.x;
  if (bid < 256) {
    __shared__ float T[64][65];
    const float* src; _Float16* dst; int spitch, ti, tj;
    if (bid < 192) { src = wq; dst = wtq; spitch = TRIPLE; ti = bid / 24; tj = bid % 24; }
    else { int t = bid - 192; src = wo; dst = wto; spitch = DIMD; ti = t >> 3; tj = t & 7; }
#pragma unroll
    for (int it = 0; it < 4; ++it) {
      int idx = it * 256 + threadIdx.x;
      int rr = idx >> 4, c4 = (idx & 15) * 4;
      *(f32x4*)&T[rr][c4] = *(const f32x4*)&src[(size_t)(ti * 64 + rr) * spitch + tj * 64 + c4];
    }
    __syncthreads();
#pragma unroll
    for (int it = 0; it < 2; ++it) {
      int idx = it * 256 + threadIdx.x;
      int rr2 = idx >> 3, c8 = (idx & 7) * 8;
      half8 o;
#pragma unroll
      for (int j = 0; j < 8; ++j) o[j] = (_Float16)T[c8 + j][rr2];
      *(half8*)&dst[(size_t)(tj * 64 + rr2) * DIMD + ti * 64 + c8] = o;
    }
    return;
  }
  int row = (bid - 256) * 4 + (threadIdx.x >> 6);
  int lane = threadIdx.x & 63;
  const float* xr = x + (size_t)row * DIMD + lane * 8;
  float v[8];
  *(f32x4*)(v)     = *(const f32x4*)(xr);
  *(f32x4*)(v + 4) = *(const f32x4*)(xr + 4);
  float s = 0.f, ss = 0.f;
#pragma unroll
  for (int j = 0; j < 8; ++j) { s += v[j]; ss += v[j] * v[j]; }
#pragma unroll
  for (int m = 1; m < 64; m <<= 1) { s += __shfl_xor(s, m); ss += __shfl_xor(ss, m); }
  float mean = s * (1.f / DIMD);
  float var  = ss * (1.f / DIMD) - mean * mean;
  float rstd = rsqrtf(var + 1e-5f);
  const float* gp = g + lane * 8;
  const float* bp = b + lane * 8;
  half8 o;
#pragma unroll
  for (int j = 0; j < 8; ++j) o[j] = (_Float16)((v[j] - mean) * rstd * gp[j] + bp[j]);
  *(half8*)(xn + (size_t)row * DIMD + lane * 8) = o;
}

// ---------------------------------------------------------------------------
// Kernel 2/4: 256x256-tile, BK=64, 8-wave phase-split pipelined GEMM
// (verified round 9 main loop). NEW: LDS-transposed coalesced epilogue
// (S is dead after the loop; vmcnt==0 at loop exit).
// ---------------------------------------------------------------------------
template <int N, int LDA, bool F32OUT>
__global__ __launch_bounds__(512, 2) void k_gemm8(const _Float16* __restrict__ A,
                                                  const _Float16* __restrict__ BT,
                                                  _Float16* __restrict__ Ch,
                                                  float* __restrict__ Cf,
                                                  const float* __restrict__ bias) {
  constexpr int NT = N / 256;
  constexpr int NWG = 256 * NT;          // NWG % 8 == 0
  constexpr int CPX = NWG / 8;
  int bb_ = blockIdx.x;
  int logical = (bb_ & 7) * CPX + (bb_ >> 3);  // bijective XCD chunking (T1)
  int mt = logical / NT, nt = logical % NT;
  int m0 = mt * 256, n0 = nt * 256;

  int tid = threadIdx.x, lane = tid & 63, w = tid >> 6;   // 8 waves
  int wrow = w >> 2, wcol = w & 3;                        // 2M x 4N
  int l15 = lane & 15, lg = lane >> 4;
  const int sr = lane >> 3;
  const int ss = lane & 7;

  __shared__ _Float16 S[65536];  // [buf0: A 16384h | B 16384h][buf1: ...]

  f32x4 acc[8][4] = {};          // [mh*4+mf][nh*2+nf]
  half8 af0[4][2], af1[4][2], bf0[2][2], bf1[2][2];

  auto stageA = [&](int d, int kt, int hf) {
#pragma unroll
    for (int cc = 0; cc < 2; ++cc) {
      int rbase = cc * 128 + hf * 64 + w * 8;
      const _Float16* gp = A + (size_t)(m0 + rbase + sr) * LDA + kt * 64 + (ss ^ sr) * 8;
      GLD16(gp, &S[d * 32768 + rbase * 64]);
    }
  };
  auto stageB = [&](int d, int kt, int hf) {
#pragma unroll
    for (int cc = 0; cc < 2; ++cc) {
      int i = cc * 64 + w * 8;
      int rbase = (i >> 5) * 64 + hf * 32 + (i & 31);
      const _Float16* gp = BT + (size_t)(n0 + rbase + sr) * 512 + kt * 64 + (ss ^ sr) * 8;
      GLD16(gp, &S[d * 32768 + 16384 + rbase * 64]);
    }
  };
  auto loadA = [&](int c, int mh, half8 (&af)[4][2]) {
#pragma unroll
    for (int mf = 0; mf < 4; ++mf) {
      int row = wrow * 128 + mh * 64 + mf * 16 + l15;  // bit6 == mh
#pragma unroll
      for (int kk = 0; kk < 2; ++kk) {
        int byte = row * 128 + ((kk * 64 + lg * 16) ^ ((row & 7) << 4));
        af[mf][kk] = *(const half8*)((const char*)&S[c * 32768] + byte);
      }
    }
  };
  auto loadB = [&](int c, int nh, half8 (&bf)[2][2]) {
#pragma unroll
    for (int nf = 0; nf < 2; ++nf) {
      int row = wcol * 64 + nh * 32 + nf * 16 + l15;   // bit5 == nh
#pragma unroll
      for (int kk = 0; kk < 2; ++kk) {
        int byte = row * 128 + ((kk * 64 + lg * 16) ^ ((row & 7) << 4));
        bf[nf][kk] = *(const half8*)((const char*)&S[c * 32768 + 16384] + byte);
      }
    }
  };
  auto quad = [&](int mh, int nh, half8 (&af)[4][2], half8 (&bf)[2][2]) {
    __builtin_amdgcn_s_setprio(1);
#pragma unroll
    for (int mf = 0; mf < 4; ++mf)
#pragma unroll
      for (int nf = 0; nf < 2; ++nf)
#pragma unroll
        for (int kk = 0; kk < 2; ++kk)
          acc[mh * 4 + mf][nh * 2 + nf] = __builtin_amdgcn_mfma_f32_16x16x32_f16(
              af[mf][kk], bf[nf][kk], acc[mh * 4 + mf][nh * 2 + nf], 0, 0, 0);
    __builtin_amdgcn_s_setprio(0);
  };

  // prologue
  stageA(0, 0, 0); stageB(0, 0, 0); stageB(0, 0, 1); stageA(0, 0, 1);
  VMW(4); BAR();

#pragma unroll
  for (int t = 0; t < 8; ++t) {
    const int c = t & 1, d = c ^ 1;
    loadA(c, 0, af0); loadB(c, 0, bf0);
    if (t > 0) quad(1, 1, af1, bf1);
    if (t < 7) { stageA(d, t + 1, 0); VMW(4); } else { VMW(2); }   // -> B1(c)
    BAR();
    loadB(c, 1, bf1);
    quad(0, 0, af0, bf0);
    if (t < 7) { stageB(d, t + 1, 0); VMW(4); } else { VMW(0); }   // -> A1(c)
    BAR();
    loadA(c, 1, af1);
    quad(0, 1, af0, bf1);
    if (t < 7) stageB(d, t + 1, 1);
    BAR();
    quad(1, 0, af1, bf0);
    if (t < 7) { stageA(d, t + 1, 1); VMW(4); }                    // -> A0,B0(d)
    BAR();
  }
  quad(1, 1, af1, bf1);   // tile 7's last quad

  // --- LDS-transposed coalesced epilogue (vmcnt == 0 here) ---
  char* Sb = (char*)S;
  if constexpr (!F32OUT) {
    __syncthreads();       // all LDS reads of S done; free (no vm outstanding)
#pragma unroll
    for (int mq = 0; mq < 8; ++mq)
#pragma unroll
      for (int nq = 0; nq < 4; ++nq)
#pragma unroll
        for (int r = 0; r < 4; ++r) {
          int row = wrow * 128 + (mq >> 2) * 64 + (mq & 3) * 16 + lg * 4 + r;
          int col = wcol * 64 + (nq >> 1) * 32 + (nq & 1) * 16 + l15;
          *(_Float16*)(Sb + row * 512 + ((col * 2) ^ ((row & 7) << 4))) =
              (_Float16)acc[mq][nq][r];
        }
    __syncthreads();
#pragma unroll
    for (int it = 0; it < 16; ++it) {
      int idx = it * 512 + tid;
      int row = idx >> 5, ch = idx & 31;
      half8 vv = *(const half8*)(Sb + row * 512 + ((ch * 16) ^ ((row & 7) << 4)));
      *(half8*)&Ch[(size_t)(m0 + row) * N + n0 + ch * 8] = vv;
    }
  } else {
    float bbv[4];
#pragma unroll
    for (int nq = 0; nq < 4; ++nq)
      bbv[nq] = bias[n0 + wcol * 64 + (nq >> 1) * 32 + (nq & 1) * 16 + l15];
    __syncthreads();       // free: vmcnt==0, lgkm reads consumed
#pragma unroll
    for (int hh = 0; hh < 2; ++hh) {
      if (hh) { LGKM0(); BAR(); }          // pass-0 stores keep draining async
#pragma unroll
      for (int m2 = 0; m2 < 4; ++m2)
#pragma unroll
        for (int nq = 0; nq < 4; ++nq)
#pragma unroll
          for (int r = 0; r < 4; ++r) {
            int packed = wrow * 64 + m2 * 16 + lg * 4 + r;     // 0..127
            int col = wcol * 64 + (nq >> 1) * 32 + (nq & 1) * 16 + l15;
            *(float*)(Sb + packed * 1024 + ((col * 4) ^ ((packed & 7) << 4))) =
                acc[hh * 4 + m2][nq][r] + bbv[nq];
          }
      LGKM0(); BAR();
#pragma unroll
      for (int it = 0; it < 16; ++it) {
        int idx = it * 512 + tid;
        int prow = idx >> 6, ch = idx & 63;
        f32x4 vv = *(const f32x4*)(Sb + prow * 1024 + ((ch * 16) ^ ((prow & 7) << 4)));
        int row = (prow >> 6) * 128 + hh * 64 + (prow & 63);
        *(f32x4*)&Cf[(size_t)(m0 + row) * N + n0 + ch * 4] = vv;
      }
    }
  }
}

// ---------------------------------------------------------------------------
// Kernel 3: fused attention with double-buffered K/V (T14 split: issue loads
// at kt top, VMW(0)+V-write after PV) and ONE barrier per kt.
// Buffer audit: after the kt-end barrier all waves are in kt+1; the writes
// (GLD K, ds_write V) target buffer d which no wave reads until after the
// NEXT barrier. Pl is per-wave (in-order DS pipe) — lgkm0+sched_barrier
// before PV as insurance. Output into dead Q columns of qkv.
// ---------------------------------------------------------------------------
__global__ __launch_bounds__(256, 2) void k_attn(_Float16* __restrict__ qkv) {
  int g = blockIdx.x >> 3, h = blockIdx.x & 7;
  int tid = threadIdx.x, lane = tid & 63, w = tid >> 6;
  int l15 = lane & 15, lg = lane >> 4;
  __shared__ _Float16 Kt[2][64 * 64];       // [key][dh], XOR-swizzled
  __shared__ _Float16 Vt[2][64 * 72];       // [dh][key], padded
  __shared__ _Float16 Pl[4][64 * 72];       // per-wave P[q][key], padded
  const size_t base = (size_t)g * NSEQ * TRIPLE;
  const int srow = lane >> 3, sslot = lane & 7;

  half8 vr[2];
  auto vload = [&](int kt) {
#pragma unroll
    for (int i = 0; i < 2; ++i) {
      int idx = tid + i * 256;
      int key = idx >> 3, dh0 = (idx & 7) * 8;
      vr[i] = *(const half8*)&qkv[base + (size_t)(kt * 64 + key) * TRIPLE + 1024 + h * 64 + dh0];
    }
  };
  auto kstage = [&](int dbuf, int kt) {
#pragma unroll
    for (int rnd = 0; rnd < 2; ++rnd) {
      int rbase = rnd * 32 + w * 8;
      const _Float16* gp = &qkv[base + (size_t)(kt * 64 + rbase + srow) * TRIPLE
                                + 512 + h * 64 + (sslot ^ srow) * 8];
      GLD16(gp, &Kt[dbuf][rbase * 64]);
    }
  };
  auto vwrite = [&](int dbuf) {
#pragma unroll
    for (int i = 0; i < 2; ++i) {
      int idx = tid + i * 256;
      int key = idx >> 3, dh0 = (idx & 7) * 8;
#pragma unroll
      for (int j = 0; j < 8; ++j) Vt[dbuf][(dh0 + j) * 72 + key] = vr[i][j];
    }
  };

  // Q fragments (B-operand layout)
  half8 qf[4][2];
#pragma unroll
  for (int nq = 0; nq < 4; ++nq)
#pragma unroll
    for (int kd = 0; kd < 2; ++kd)
      qf[nq][kd] = *(const half8*)&qkv[base + (size_t)(w * 64 + nq * 16 + l15) * TRIPLE
                                       + h * 64 + kd * 32 + lg * 8];

  f32x4 oacc[4][4] = {};
  float mrun[4], lrun[4];
#pragma unroll
  for (int nq = 0; nq < 4; ++nq) { mrun[nq] = -3.0e38f; lrun[nq] = 0.f; }

  // prologue: stage kt=0 into buffer 0
  kstage(0, 0); vload(0);
  VMW(0);
  vwrite(0);
  LGKM0(); BAR();

  for (int kt = 0; kt < 4; ++kt) {
    const int c = kt & 1, d = c ^ 1;
    if (kt < 3) { kstage(d, kt + 1); vload(kt + 1); }

    // S^T = K * Q^T from Kt[c] (swizzled reads)
    f32x4 st[4][4] = {};
#pragma unroll
    for (int kd = 0; kd < 2; ++kd) {
      half8 kf[4];
#pragma unroll
      for (int mk = 0; mk < 4; ++mk) {
        int r = mk * 16 + l15;
        int byte = r * 128 + ((kd * 64 + lg * 16) ^ ((r & 7) << 4));
        kf[mk] = *(const half8*)((const char*)Kt[c] + byte);
      }
#pragma unroll
      for (int mk = 0; mk < 4; ++mk)
#pragma unroll
        for (int nq = 0; nq < 4; ++nq)
          st[mk][nq] = __builtin_amdgcn_mfma_f32_16x16x32_f16(kf[mk], qf[nq][kd], st[mk][nq], 0, 0, 0);
    }

    // online softmax per q column
    float alpha[4];
#pragma unroll
    for (int nq = 0; nq < 4; ++nq) {
      float pm = -3.0e38f;
#pragma unroll
      for (int mk = 0; mk < 4; ++mk)
#pragma unroll
        for (int r = 0; r < 4; ++r) {
          st[mk][nq][r] *= ATT_SCALE;
          pm = fmaxf(pm, st[mk][nq][r]);
        }
      pm = fmaxf(pm, __shfl_xor(pm, 16));
      pm = fmaxf(pm, __shfl_xor(pm, 32));
      float mn = fmaxf(mrun[nq], pm);
      alpha[nq] = __expf(mrun[nq] - mn);
      mrun[nq] = mn;
      float ps = 0.f;
#pragma unroll
      for (int mk = 0; mk < 4; ++mk) {
        half4 p4;
#pragma unroll
        for (int r = 0; r < 4; ++r) {
          float e = __expf(st[mk][nq][r] - mn);
          ps += e;
          p4[r] = (_Float16)e;
        }
        *(half4*)&Pl[w][(nq * 16 + l15) * 72 + mk * 16 + lg * 4] = p4;
      }
      ps += __shfl_xor(ps, 16);
      ps += __shfl_xor(ps, 32);
      lrun[nq] = lrun[nq] * alpha[nq] + ps;
    }

    // rescale O
#pragma unroll
    for (int mp = 0; mp < 4; ++mp)
#pragma unroll
      for (int r = 0; r < 4; ++r) {
        float av = __shfl(alpha[mp], lg * 4 + r);
#pragma unroll
        for (int nd = 0; nd < 4; ++nd) oacc[mp][nd][r] *= av;
      }

    LGKM0();                                   // Pl writes committed (own wave)
    __builtin_amdgcn_sched_barrier(0);

    // O += P * V from Vt[c]
#pragma unroll
    for (int kp = 0; kp < 2; ++kp) {
      int co = kp * 32 + lg * 8;
      half8 pf[4], vf[4];
#pragma unroll
      for (int mp = 0; mp < 4; ++mp) pf[mp] = *(const half8*)&Pl[w][(mp * 16 + l15) * 72 + co];
#pragma unroll
      for (int nd = 0; nd < 4; ++nd) vf[nd] = *(const half8*)&Vt[c][(nd * 16 + l15) * 72 + co];
#pragma unroll
      for (int mp = 0; mp < 4; ++mp)
#pragma unroll
        for (int nd = 0; nd < 4; ++nd)
          oacc[mp][nd] = __builtin_amdgcn_mfma_f32_16x16x32_f16(pf[mp], vf[nd], oacc[mp][nd], 0, 0, 0);
    }

    if (kt < 3) { VMW(0); vwrite(d); }         // loads hidden under compute
    LGKM0(); BAR();                            // publish Vt[d] / Kt[d]
  }

  // epilogue: normalize and write att into the Q columns (stride TRIPLE)
#pragma unroll
  for (int mp = 0; mp < 4; ++mp)
#pragma unroll
    for (int r = 0; r < 4; ++r) {
      float li = 1.f / __shfl(lrun[mp], lg * 4 + r);
      int q = w * 64 + mp * 16 + lg * 4 + r;
#pragma unroll
      for (int nd = 0; nd < 4; ++nd)
        qkv[base + (size_t)q * TRIPLE + h * 64 + nd * 16 + l15] =
            (_Float16)(oacc[mp][nd][r] * li);
    }
}

// ---------------------------------------------------------------------------
extern "C" void kernel_launch(void* const* d_in, const int* in_sizes, int n_in,
                              void* d_out, int out_size, void* d_ws, size_t ws_size,
                              hipStream_t stream) {
  const float* x     = (const float*)d_in[0];
  const float* ln_g  = (const float*)d_in[1];
  const float* ln_b  = (const float*)d_in[2];
  const float* w_qkv = (const float*)d_in[3];
  const float* w_out = (const float*)d_in[4];
  const float* b_out = (const float*)d_in[5];

  // workspace (~194 MB): qkv fp16 [65536][1536] (att overwrites Q cols);
  // w_qkv^T fp16; w_out^T fp16. d_out f32 [65536][512]; first 64MB = xn fp16.
  char* ws = (char*)d_ws;
  _Float16* qkv = (_Float16*)ws;
  _Float16* wtq = (_Float16*)(ws + 201326592ull);
  _Float16* wto = (_Float16*)(ws + 201326592ull + 1572864ull);
  _Float16* xn  = (_Float16*)d_out;
  float* out    = (float*)d_out;

  k_pre<<<16640, 256, 0, stream>>>(x, ln_g, ln_b, w_qkv, w_out, xn, wtq, wto);
  k_gemm8<TRIPLE, DIMD, false><<<1536, 512, 0, stream>>>(xn, wtq, qkv, nullptr, nullptr);
  k_attn<<<2048, 256, 0, stream>>>(qkv);
  k_gemm8<DIMD, TRIPLE, true><<<512, 512, 0, stream>>>(qkv, wto, nullptr, out, b_out);
}